// Round 16
// baseline (155.709 us; speedup 1.0000x reference)
//
#include <hip/hip_runtime.h>
#include <hip/hip_bf16.h>

// MPNNConv (R15 dataflow; out fused into layer1 via 16-node LDS batch + MFMA):
//   s[n] = h[n] @ W1[0:128] + b1 (f32 swz), g[n] = h[n] @ W1[128:256] (bf16 swz, L2-resident)
//   Hsum[n] = sum_{e: rows[e]=n} relu(s[n] + g[cols[e]] + ef[e] @ W1e)   (K=32 bf16 MFMA)
//   out[n]  = Hsum[n] @ W2 + deg[n]*b2
// CSR on-device; ef permuted into CSR order as bf16 (efb, 64B full-line records)
// + ccol. layer1out: 256-thread blocks own 16 nodes; 4 waves x 4 nodes run the
// R15 1-wave full-row loop -> Hsum rows into LDS hs[16][132] (padded stride);
// sync; 16x128 out-tile via MFMA (8/wave) -- NOT R12's per-node VALU GEMV.
// Removes out_kernel launch + 10MB hsum round-trip.
// counts zeroed by hipMemsetAsync BEFORE prep_hist (R11 cross-block race).

typedef __attribute__((ext_vector_type(8))) short bf16x8;
typedef __attribute__((ext_vector_type(4))) float f32x4;

#define ND 128
#define ED 32

__device__ __forceinline__ short f2bf(float x) {
  unsigned int u = __float_as_uint(x);
  unsigned int r = (u + 0x7FFFu + ((u >> 16) & 1u)) >> 16;
  return (short)r;
}

__device__ __forceinline__ float bf2f(short s) {
  return __uint_as_float(((unsigned int)(unsigned short)s) << 16);
}

__device__ __forceinline__ f32x4 bf8lo(bf16x8 v) {
  f32x4 r;
  #pragma unroll
  for (int j = 0; j < 4; ++j) r[j] = bf2f(v[j]);
  return r;
}
__device__ __forceinline__ f32x4 bf8hi(bf16x8 v) {
  f32x4 r;
  #pragma unroll
  for (int j = 0; j < 4; ++j) r[j] = bf2f(v[4 + j]);
  return r;
}

// swizzled offset within a 128-wide row for col c (c = ct*16 + cc)
__device__ __forceinline__ int swz(int c) {
  int ct = c >> 4, cc = c & 15;
  return (ct >> 2) * 64 + (cc >> 2) * 16 + (ct & 3) * 4 + (cc & 3);
}

// --- fused: weight pre-layouts (blocks [0,128)) | hist/rank/rc (rest) ---
__global__ __launch_bounds__(256) void prep_hist_kernel(
    const float* __restrict__ W1, const float* __restrict__ W2,
    const void* __restrict__ ei, int* __restrict__ counts,
    int* __restrict__ rank, unsigned int* __restrict__ rc,
    short* __restrict__ w12t, short* __restrict__ w1eA, short* __restrict__ w2t,
    int E) {
  int b = blockIdx.x;
  if (b < 128) {
    int t = b * 256 + threadIdx.x;
    if (t < 256 * 128) {  // w12t[n'][k]: n'<128 -> W1[k][n'] ; else W1[128+k][n'-128]
      int np = t >> 7, k = t & 127;
      float v = (np < 128) ? W1[k * 128 + np] : W1[(128 + k) * 128 + (np - 128)];
      w12t[t] = f2bf(v);
    }
    if (t < 128 * 128) {  // w2t[n][k] = W2[k][n]
      int n = t >> 7, k = t & 127;
      w2t[t] = f2bf(W2[k * 128 + n]);
    }
    if (t < 8 * 64 * 8) { // w1eA[ct][lane][j] = W1[256+lg*8+j][ct*16+li]
      int ct = t >> 9, lane = (t >> 3) & 63, j = t & 7;
      int li = lane & 15, lg = lane >> 4;
      w1eA[t] = f2bf(W1[(256 + lg * 8 + j) * 128 + ct * 16 + li]);
    }
  } else {
    int e = (b - 128) * 256 + threadIdx.x;
    if (e < E) {
      const unsigned int* u = (const unsigned int*)ei;
      int is64 = 1;
      #pragma unroll
      for (int i = 0; i < 16; ++i)
        if (u[2 * i + 1] != 0u) is64 = 0;   // uniform addresses -> scalar loads
      int r, c;
      if (is64) {
        r = (int)((const long long*)ei)[e];
        c = (int)((const long long*)ei)[(long long)E + e];
      } else {
        r = ((const int*)ei)[e];
        c = ((const int*)ei)[E + e];
      }
      rank[e] = atomicAdd(&counts[r], 1);
      rc[e] = ((unsigned int)r << 16) | (unsigned int)c;   // N < 65536
    }
  }
}

// --- single-block scan: 1024 threads x 16 elems ---
__global__ __launch_bounds__(1024) void scan_kernel(const int* __restrict__ counts,
                                                    int* __restrict__ row_ptr, int n) {
  __shared__ int wtot[16];
  int tid = threadIdx.x;
  int lane = tid & 63, w = tid >> 6;
  int base_i = tid * 16;
  int c[16];
  int tot = 0;
  #pragma unroll
  for (int j = 0; j < 16; ++j) {
    int i = base_i + j;
    c[j] = (i < n) ? counts[i] : 0;
    tot += c[j];
  }
  int x = tot;
  #pragma unroll
  for (int d = 1; d < 64; d <<= 1) {
    int t = __shfl_up(x, d);
    if (lane >= d) x += t;
  }
  if (lane == 63) wtot[w] = x;
  __syncthreads();
  if (w == 0) {
    int y = (lane < 16) ? wtot[lane] : 0;
    #pragma unroll
    for (int d = 1; d < 16; d <<= 1) {
      int t = __shfl_up(y, d);
      if (lane >= d) y += t;
    }
    if (lane < 16) wtot[lane] = y;
  }
  __syncthreads();
  int waveoff = (w == 0) ? 0 : wtot[w - 1];
  int run = waveoff + x - tot;  // exclusive prefix
  if (tid == 0) row_ptr[0] = 0;
  #pragma unroll
  for (int j = 0; j < 16; ++j) {
    int i = base_i + j;
    if (i < n) {
      run += c[j];
      row_ptr[i + 1] = run;
    }
  }
}

// --- fused: sg GEMM (blocks [0,SGB)) + ef->efb bf16 permute (rest) ---
__global__ __launch_bounds__(256, 4) void scatter_sg_kernel(
    const float* __restrict__ ef, const int* __restrict__ row_ptr,
    const int* __restrict__ rank, const unsigned int* __restrict__ rc,
    const float* __restrict__ h, const short* __restrict__ w12t,
    const float* __restrict__ b1, short* __restrict__ efb,
    int* __restrict__ ccol, float* __restrict__ s2, short* __restrict__ g2,
    int N, int E) {
  int b = blockIdx.x;
  int SGB = (N + 63) >> 6;
  if (b < SGB) {
    // ---- s = h@W1top + b1 (f32 swz), g = h@W1mid (bf16 swz)
    int lane = threadIdx.x & 63, w = threadIdx.x >> 6;
    int li = lane & 15, lg = lane >> 4;
    int base = b * 64 + w * 16;
    int rowm = base + li;
    if (rowm >= N) rowm = N - 1;
    float breg[8];
    #pragma unroll
    for (int nt = 0; nt < 8; ++nt) breg[nt] = b1[nt * 16 + li];
    f32x4 acc[16];
    #pragma unroll
    for (int nt = 0; nt < 16; ++nt) acc[nt] = (f32x4){0.f, 0.f, 0.f, 0.f};
    #pragma unroll
    for (int kc = 0; kc < 4; ++kc) {
      f32x4 f0 = *(const f32x4*)(h + (size_t)rowm * ND + kc * 32 + lg * 8);
      f32x4 f1 = *(const f32x4*)(h + (size_t)rowm * ND + kc * 32 + lg * 8 + 4);
      bf16x8 a;
      #pragma unroll
      for (int j = 0; j < 4; ++j) { a[j] = f2bf(f0[j]); a[4 + j] = f2bf(f1[j]); }
      #pragma unroll
      for (int nt = 0; nt < 16; ++nt) {
        bf16x8 bb = *(const bf16x8*)(w12t + (nt * 16 + li) * 128 + kc * 32 + lg * 8);
        acc[nt] = __builtin_amdgcn_mfma_f32_16x16x32_bf16(a, bb, acc[nt], 0, 0, 0);
      }
    }
    #pragma unroll
    for (int nt = 0; nt < 16; ++nt)
      #pragma unroll
      for (int r = 0; r < 4; ++r) {
        int row = base + lg * 4 + r;
        if (row < N) {
          if (nt < 8) {
            s2[(size_t)row * 128 + swz(nt * 16 + li)] = acc[nt][r] + breg[nt];
          } else {
            g2[(size_t)row * 128 + swz((nt - 8) * 16 + li)] = f2bf(acc[nt][r]);
          }
        }
      }
  } else {
    // ---- permute: 4 threads/edge; coalesced ef read, full-line scattered write
    int gt = (b - SGB) * 256 + threadIdx.x;
    int e = gt >> 2, part = gt & 3;
    if (e < E) {
      unsigned int p = rc[e];
      int r = (int)(p >> 16), c = (int)(p & 0xffffu);
      int pos = row_ptr[r] + rank[e];
      f32x4 a0 = *(const f32x4*)(ef + (size_t)e * ED + part * 8);
      f32x4 a1 = *(const f32x4*)(ef + (size_t)e * ED + part * 8 + 4);
      bf16x8 ob;
      #pragma unroll
      for (int j = 0; j < 4; ++j) { ob[j] = f2bf(a0[j]); ob[4 + j] = f2bf(a1[j]); }
      *(bf16x8*)(efb + (size_t)pos * ED + part * 8) = ob;
      if (part == 0) ccol[pos] = c;
    }
  }
}

// --- layer1 + segment reduce + fused out: block = 16 nodes, 4 waves x 4 nodes;
//     per-node R15 full-row loop -> Hsum rows in LDS; then 16x128 out-tile MFMA ---
__global__ __launch_bounds__(256) void layer1out_kernel(
    const float* __restrict__ s2, const short* __restrict__ g2,
    const short* __restrict__ efb, const int* __restrict__ ccol,
    const short* __restrict__ w1eA, const short* __restrict__ w2t,
    const float* __restrict__ b2, const int* __restrict__ row_ptr,
    float* __restrict__ out, int N) {
  __shared__ float hs[16][132];   // padded stride: <=2-way LDS bank aliasing
  int tid = threadIdx.x;
  int wv = tid >> 6;
  int lane = tid & 63;
  int li = lane & 15, lg = lane >> 4;

  // W1e frags (node-invariant, all 8 col-tiles)
  bf16x8 wa[8];
  #pragma unroll
  for (int ct = 0; ct < 8; ++ct)
    wa[ct] = *(const bf16x8*)(w1eA + (ct * 64 + lane) * 8);
  // b2 frags for this wave's 2 out col-tiles
  float breg[2];
  #pragma unroll
  for (int nt = 0; nt < 2; ++nt) breg[nt] = b2[(wv * 2 + nt) * 16 + li];

  for (int nb = blockIdx.x * 16; nb < N; nb += gridDim.x * 16) {
    // ---- phase 1: each wave computes Hsum rows for its 4 nodes into LDS
    #pragma unroll 1
    for (int i = 0; i < 4; ++i) {
      int node = nb + wv * 4 + i;
      int lrow = wv * 4 + i;
      if (node >= N) {
        if (li == 0) {
          #pragma unroll
          for (int ct = 0; ct < 8; ++ct)
            *(f32x4*)(&hs[lrow][ct * 16 + lg * 4]) = (f32x4){0.f, 0.f, 0.f, 0.f};
        }
        continue;
      }
      int rp = row_ptr[node], rpe = row_ptr[node + 1];
      int deg = rpe - rp;
      if (deg == 0) {
        if (li == 0) {
          #pragma unroll
          for (int ct = 0; ct < 8; ++ct)
            *(f32x4*)(&hs[lrow][ct * 16 + lg * 4]) = (f32x4){0.f, 0.f, 0.f, 0.f};
        }
        continue;
      }

      f32x4 sreg[8];
      #pragma unroll
      for (int ct = 0; ct < 8; ++ct)
        sreg[ct] = *(const f32x4*)(s2 + (size_t)node * 128 +
                                   (ct >> 2) * 64 + lg * 16 + (ct & 3) * 4);
      f32x4 psum[8];
      #pragma unroll
      for (int ct = 0; ct < 8; ++ct) psum[ct] = (f32x4){0.f, 0.f, 0.f, 0.f};

      int ntiles = (deg + 15) >> 4;
      int last = rpe - 1;
      auto ldpos = [&](int t) {
        int p = rp + t * 16 + li;
        return p > last ? last : p;
      };

      int pA = ldpos(0), pB = ldpos(1);
      int cA = ccol[pA], cB = ccol[pB];
      bf16x8 eA = *(const bf16x8*)(efb + (size_t)pA * ED + lg * 8);
      bf16x8 eB = *(const bf16x8*)(efb + (size_t)pB * ED + lg * 8);
      const short* gpA = g2 + (size_t)cA * 128;
      bf16x8 gA0 = *(const bf16x8*)(gpA + lg * 16);
      bf16x8 gA1 = *(const bf16x8*)(gpA + lg * 16 + 8);
      bf16x8 gA2 = *(const bf16x8*)(gpA + 64 + lg * 16);
      bf16x8 gA3 = *(const bf16x8*)(gpA + 64 + lg * 16 + 8);

      for (int t = 0; t < ntiles; ++t) {
        const short* gpB = g2 + (size_t)cB * 128;
        bf16x8 gB0 = *(const bf16x8*)(gpB + lg * 16);
        bf16x8 gB1 = *(const bf16x8*)(gpB + lg * 16 + 8);
        bf16x8 gB2 = *(const bf16x8*)(gpB + 64 + lg * 16);
        bf16x8 gB3 = *(const bf16x8*)(gpB + 64 + lg * 16 + 8);
        int pC = ldpos(t + 2);
        int cC = ccol[pC];
        bf16x8 eC = *(const bf16x8*)(efb + (size_t)pC * ED + lg * 8);
        f32x4 acc[8];
        #pragma unroll
        for (int ct = 0; ct < 8; ++ct)
          acc[ct] = __builtin_amdgcn_mfma_f32_16x16x32_bf16(
              wa[ct], eA, (f32x4){0.f, 0.f, 0.f, 0.f}, 0, 0, 0);
        if ((t * 16 + li) < deg) {
          #pragma unroll
          for (int ct = 0; ct < 8; ++ct) {
            bf16x8 gr = (ct < 4) ? ((ct & 2) ? gA1 : gA0) : ((ct & 2) ? gA3 : gA2);
            f32x4 gv = (ct & 1) ? bf8hi(gr) : bf8lo(gr);
            f32x4 v = acc[ct] + sreg[ct] + gv;
            #pragma unroll
            for (int r = 0; r < 4; ++r)
              psum[ct][r] += (v[r] > 0.f ? v[r] : 0.f);
          }
        }
        cB = cC; eA = eB; eB = eC;
        gA0 = gB0; gA1 = gB1; gA2 = gB2; gA3 = gB3;
      }

      #pragma unroll
      for (int ct = 0; ct < 8; ++ct)
        #pragma unroll
        for (int r = 0; r < 4; ++r) {
          float v = psum[ct][r];
          v += __shfl_xor(v, 1);
          v += __shfl_xor(v, 2);
          v += __shfl_xor(v, 4);
          v += __shfl_xor(v, 8);
          psum[ct][r] = v;
        }
      if (li == 0) {
        #pragma unroll
        for (int ct = 0; ct < 8; ++ct)
          *(f32x4*)(&hs[lrow][ct * 16 + lg * 4]) = psum[ct];
      }
    }
    __syncthreads();

    // ---- phase 2: 16x128 out-tile; wave wv covers col-tiles 2wv, 2wv+1
    f32x4 oacc[2];
    #pragma unroll
    for (int nt = 0; nt < 2; ++nt) oacc[nt] = (f32x4){0.f, 0.f, 0.f, 0.f};
    #pragma unroll
    for (int kc = 0; kc < 4; ++kc) {
      bf16x8 a;
      #pragma unroll
      for (int j = 0; j < 8; ++j) a[j] = f2bf(hs[li][kc * 32 + lg * 8 + j]);
      #pragma unroll
      for (int nt = 0; nt < 2; ++nt) {
        bf16x8 bb = *(const bf16x8*)(w2t + ((wv * 2 + nt) * 16 + li) * 128 +
                                     kc * 32 + lg * 8);
        oacc[nt] = __builtin_amdgcn_mfma_f32_16x16x32_bf16(a, bb, oacc[nt], 0, 0, 0);
      }
    }
    #pragma unroll
    for (int r = 0; r < 4; ++r) {
      int row = nb + lg * 4 + r;
      if (row < N) {
        float dg = (float)(row_ptr[row + 1] - row_ptr[row]);
        #pragma unroll
        for (int nt = 0; nt < 2; ++nt)
          out[(size_t)row * 128 + (wv * 2 + nt) * 16 + li] = oacc[nt][r] + dg * breg[nt];
      }
    }
    __syncthreads();   // hs reuse safety for next batch
  }
}

extern "C" void kernel_launch(void* const* d_in, const int* in_sizes, int n_in,
                              void* d_out, int out_size, void* d_ws, size_t ws_size,
                              hipStream_t stream) {
  const float* h  = (const float*)d_in[0];
  const void*  ei = d_in[1];
  const float* ef = (const float*)d_in[2];
  const float* W1 = (const float*)d_in[4];
  const float* b1 = (const float*)d_in[5];
  const float* W2 = (const float*)d_in[6];
  const float* b2 = (const float*)d_in[7];
  float* out = (float*)d_out;
  int N = in_sizes[0] / ND;
  int E = in_sizes[2] / ED;

  char* ws = (char*)d_ws;
  size_t off = 0;
  auto alloc = [&](size_t bytes) {
    size_t o = off;
    off = (off + bytes + 255) & ~(size_t)255;
    return o;
  };
  int*          counts  = (int*)(ws + alloc((size_t)N * 4));
  int*          row_ptr = (int*)(ws + alloc((size_t)(N + 1) * 4));
  int*          rank    = (int*)(ws + alloc((size_t)E * 4));
  unsigned int* rc      = (unsigned int*)(ws + alloc((size_t)E * 4));
  short*        w12t    = (short*)(ws + alloc(256 * 128 * 2));
  short*        w1eA    = (short*)(ws + alloc(8 * 64 * 8 * 2));
  short*        w2t     = (short*)(ws + alloc(128 * 128 * 2));
  float*        s2      = (float*)(ws + alloc((size_t)N * 128 * 4));
  short*        g2      = (short*)(ws + alloc((size_t)N * 128 * 2));
  short*        efb     = (short*)(ws + alloc((size_t)E * ED * 2));
  int*          ccol    = (int*)(ws + alloc((size_t)E * 4));

  int SGB = (N + 63) >> 6;
  int SCB = (4 * E + 255) >> 8;
  int NLB = (N + 15) >> 4;

  hipMemsetAsync(counts, 0, (size_t)N * 4, stream);   // MUST precede prep_hist (R11 race)
  prep_hist_kernel<<<128 + (E + 255) / 256, 256, 0, stream>>>(
      W1, W2, ei, counts, rank, rc, w12t, w1eA, w2t, E);
  scan_kernel<<<1, 1024, 0, stream>>>(counts, row_ptr, N);
  scatter_sg_kernel<<<SGB + SCB, 256, 0, stream>>>(
      ef, row_ptr, rank, rc, h, w12t, b1, efb, ccol, s2, g2, N, E);
  layer1out_kernel<<<NLB, 256, 0, stream>>>(
      s2, g2, efb, ccol, w1eA, w2t, b2, row_ptr, out, N);
}

// Round 17
// 133.958 us; speedup vs baseline: 1.1624x; 1.1624x over previous
//
#include <hip/hip_runtime.h>
#include <hip/hip_bf16.h>

// MPNNConv FINAL (R14 champion, best measured 133.65us):
//   s[n] = h[n] @ W1[0:128] + b1 (f32 swz), g[n] = h[n] @ W1[128:256] (bf16 swz, L2-resident)
//   Hsum[n] = sum_{e: rows[e]=n} relu(s[n] + g[cols[e]] + ef[e] @ W1e)   (K=32 bf16 MFMA)
//   out[n]  = Hsum[n] @ W2 + deg[n]*b2
// CSR on-device; ef permuted into CSR order as bf16 (efb, 64B full-line records)
// + ccol. layer1: 2048 persistent 2-wave blocks grid-striding over nodes.
// Measured primitive hierarchy driving this design: coalesced stream >>
// scattered full-line writes (2.3 TB/s) >> dependent gathers (~1 TB/s) >>
// global f32 atomics (write-through to HBM). Fusing out into layer1 regressed
// twice (R12 VALU-GEMV, R16 occupancy); keep the separate MFMA out_kernel.
// counts zeroed by hipMemsetAsync BEFORE prep_hist (R11 cross-block race).

typedef __attribute__((ext_vector_type(8))) short bf16x8;
typedef __attribute__((ext_vector_type(4))) float f32x4;

#define ND 128
#define ED 32
#define NL1 2048   // persistent layer1 blocks

__device__ __forceinline__ short f2bf(float x) {
  unsigned int u = __float_as_uint(x);
  unsigned int r = (u + 0x7FFFu + ((u >> 16) & 1u)) >> 16;
  return (short)r;
}

__device__ __forceinline__ float bf2f(short s) {
  return __uint_as_float(((unsigned int)(unsigned short)s) << 16);
}

__device__ __forceinline__ f32x4 bf8lo(bf16x8 v) {
  f32x4 r;
  #pragma unroll
  for (int j = 0; j < 4; ++j) r[j] = bf2f(v[j]);
  return r;
}
__device__ __forceinline__ f32x4 bf8hi(bf16x8 v) {
  f32x4 r;
  #pragma unroll
  for (int j = 0; j < 4; ++j) r[j] = bf2f(v[4 + j]);
  return r;
}

// swizzled offset within a 128-wide row for col c (c = ct*16 + cc)
__device__ __forceinline__ int swz(int c) {
  int ct = c >> 4, cc = c & 15;
  return (ct >> 2) * 64 + (cc >> 2) * 16 + (ct & 3) * 4 + (cc & 3);
}

// --- fused: weight pre-layouts (blocks [0,128)) | hist/rank/rc (rest) ---
__global__ __launch_bounds__(256) void prep_hist_kernel(
    const float* __restrict__ W1, const float* __restrict__ W2,
    const void* __restrict__ ei, int* __restrict__ counts,
    int* __restrict__ rank, unsigned int* __restrict__ rc,
    short* __restrict__ w12t, short* __restrict__ w1eA, short* __restrict__ w2t,
    int E) {
  int b = blockIdx.x;
  if (b < 128) {
    int t = b * 256 + threadIdx.x;
    if (t < 256 * 128) {  // w12t[n'][k]: n'<128 -> W1[k][n'] ; else W1[128+k][n'-128]
      int np = t >> 7, k = t & 127;
      float v = (np < 128) ? W1[k * 128 + np] : W1[(128 + k) * 128 + (np - 128)];
      w12t[t] = f2bf(v);
    }
    if (t < 128 * 128) {  // w2t[n][k] = W2[k][n]
      int n = t >> 7, k = t & 127;
      w2t[t] = f2bf(W2[k * 128 + n]);
    }
    if (t < 8 * 64 * 8) { // w1eA[ct][lane][j] = W1[256+lg*8+j][ct*16+li]
      int ct = t >> 9, lane = (t >> 3) & 63, j = t & 7;
      int li = lane & 15, lg = lane >> 4;
      w1eA[t] = f2bf(W1[(256 + lg * 8 + j) * 128 + ct * 16 + li]);
    }
  } else {
    int e = (b - 128) * 256 + threadIdx.x;
    if (e < E) {
      const unsigned int* u = (const unsigned int*)ei;
      int is64 = 1;
      #pragma unroll
      for (int i = 0; i < 16; ++i)
        if (u[2 * i + 1] != 0u) is64 = 0;   // uniform addresses -> scalar loads
      int r, c;
      if (is64) {
        r = (int)((const long long*)ei)[e];
        c = (int)((const long long*)ei)[(long long)E + e];
      } else {
        r = ((const int*)ei)[e];
        c = ((const int*)ei)[E + e];
      }
      rank[e] = atomicAdd(&counts[r], 1);
      rc[e] = ((unsigned int)r << 16) | (unsigned int)c;   // N < 65536
    }
  }
}

// --- single-block scan: 1024 threads x 16 elems ---
__global__ __launch_bounds__(1024) void scan_kernel(const int* __restrict__ counts,
                                                    int* __restrict__ row_ptr, int n) {
  __shared__ int wtot[16];
  int tid = threadIdx.x;
  int lane = tid & 63, w = tid >> 6;
  int base_i = tid * 16;
  int c[16];
  int tot = 0;
  #pragma unroll
  for (int j = 0; j < 16; ++j) {
    int i = base_i + j;
    c[j] = (i < n) ? counts[i] : 0;
    tot += c[j];
  }
  int x = tot;
  #pragma unroll
  for (int d = 1; d < 64; d <<= 1) {
    int t = __shfl_up(x, d);
    if (lane >= d) x += t;
  }
  if (lane == 63) wtot[w] = x;
  __syncthreads();
  if (w == 0) {
    int y = (lane < 16) ? wtot[lane] : 0;
    #pragma unroll
    for (int d = 1; d < 16; d <<= 1) {
      int t = __shfl_up(y, d);
      if (lane >= d) y += t;
    }
    if (lane < 16) wtot[lane] = y;
  }
  __syncthreads();
  int waveoff = (w == 0) ? 0 : wtot[w - 1];
  int run = waveoff + x - tot;  // exclusive prefix
  if (tid == 0) row_ptr[0] = 0;
  #pragma unroll
  for (int j = 0; j < 16; ++j) {
    int i = base_i + j;
    if (i < n) {
      run += c[j];
      row_ptr[i + 1] = run;
    }
  }
}

// --- fused: sg GEMM (blocks [0,SGB)) + ef->efb bf16 permute (rest) ---
__global__ __launch_bounds__(256, 4) void scatter_sg_kernel(
    const float* __restrict__ ef, const int* __restrict__ row_ptr,
    const int* __restrict__ rank, const unsigned int* __restrict__ rc,
    const float* __restrict__ h, const short* __restrict__ w12t,
    const float* __restrict__ b1, short* __restrict__ efb,
    int* __restrict__ ccol, float* __restrict__ s2, short* __restrict__ g2,
    int N, int E) {
  int b = blockIdx.x;
  int SGB = (N + 63) >> 6;
  if (b < SGB) {
    // ---- s = h@W1top + b1 (f32 swz), g = h@W1mid (bf16 swz)
    int lane = threadIdx.x & 63, w = threadIdx.x >> 6;
    int li = lane & 15, lg = lane >> 4;
    int base = b * 64 + w * 16;
    int rowm = base + li;
    if (rowm >= N) rowm = N - 1;
    float breg[8];
    #pragma unroll
    for (int nt = 0; nt < 8; ++nt) breg[nt] = b1[nt * 16 + li];
    f32x4 acc[16];
    #pragma unroll
    for (int nt = 0; nt < 16; ++nt) acc[nt] = (f32x4){0.f, 0.f, 0.f, 0.f};
    #pragma unroll
    for (int kc = 0; kc < 4; ++kc) {
      f32x4 f0 = *(const f32x4*)(h + (size_t)rowm * ND + kc * 32 + lg * 8);
      f32x4 f1 = *(const f32x4*)(h + (size_t)rowm * ND + kc * 32 + lg * 8 + 4);
      bf16x8 a;
      #pragma unroll
      for (int j = 0; j < 4; ++j) { a[j] = f2bf(f0[j]); a[4 + j] = f2bf(f1[j]); }
      #pragma unroll
      for (int nt = 0; nt < 16; ++nt) {
        bf16x8 bb = *(const bf16x8*)(w12t + (nt * 16 + li) * 128 + kc * 32 + lg * 8);
        acc[nt] = __builtin_amdgcn_mfma_f32_16x16x32_bf16(a, bb, acc[nt], 0, 0, 0);
      }
    }
    #pragma unroll
    for (int nt = 0; nt < 16; ++nt)
      #pragma unroll
      for (int r = 0; r < 4; ++r) {
        int row = base + lg * 4 + r;
        if (row < N) {
          if (nt < 8) {
            s2[(size_t)row * 128 + swz(nt * 16 + li)] = acc[nt][r] + breg[nt];
          } else {
            g2[(size_t)row * 128 + swz((nt - 8) * 16 + li)] = f2bf(acc[nt][r]);
          }
        }
      }
  } else {
    // ---- permute: 4 threads/edge; coalesced ef read, full-line scattered write
    int gt = (b - SGB) * 256 + threadIdx.x;
    int e = gt >> 2, part = gt & 3;
    if (e < E) {
      unsigned int p = rc[e];
      int r = (int)(p >> 16), c = (int)(p & 0xffffu);
      int pos = row_ptr[r] + rank[e];
      f32x4 a0 = *(const f32x4*)(ef + (size_t)e * ED + part * 8);
      f32x4 a1 = *(const f32x4*)(ef + (size_t)e * ED + part * 8 + 4);
      bf16x8 ob;
      #pragma unroll
      for (int j = 0; j < 4; ++j) { ob[j] = f2bf(a0[j]); ob[4 + j] = f2bf(a1[j]); }
      *(bf16x8*)(efb + (size_t)pos * ED + part * 8) = ob;
      if (part == 0) ccol[pos] = c;
    }
  }
}

// --- layer 1 + segment reduce: PERSISTENT blocks grid-striding over nodes,
//     2 waves (col halves), efb/ccol streamed, g gathered from L2 ---
__global__ __launch_bounds__(128, 4) void layer1_kernel(
    const float* __restrict__ s2, const short* __restrict__ g2,
    const short* __restrict__ efb, const int* __restrict__ ccol,
    const short* __restrict__ w1eA, const int* __restrict__ row_ptr,
    float* __restrict__ hsum, int N) {
  int lane = threadIdx.x & 63;
  int w = threadIdx.x >> 6;  // col half 0/1
  int li = lane & 15, lg = lane >> 4;

  // weights are node-invariant: load once per block lifetime
  bf16x8 wa[4];
  #pragma unroll
  for (int nt = 0; nt < 4; ++nt)
    wa[nt] = *(const bf16x8*)(w1eA + ((w * 4 + nt) * 64 + lane) * 8);

  for (int node = blockIdx.x; node < N; node += NL1) {
    int rp = row_ptr[node], rpe = row_ptr[node + 1];
    int deg = rpe - rp;

    if (deg == 0) {
      if (li == 0) {
        #pragma unroll
        for (int nt = 0; nt < 4; ++nt)
          *(f32x4*)(hsum + (size_t)node * 128 + w * 64 + nt * 16 + lg * 4) =
              (f32x4){0.f, 0.f, 0.f, 0.f};
      }
      continue;
    }

    f32x4 sreg[4];
    #pragma unroll
    for (int nt = 0; nt < 4; ++nt)
      sreg[nt] = *(const f32x4*)(s2 + (size_t)node * 128 + w * 64 + lg * 16 + nt * 4);
    f32x4 psum[4];
    #pragma unroll
    for (int nt = 0; nt < 4; ++nt) psum[nt] = (f32x4){0.f, 0.f, 0.f, 0.f};

    int ntiles = (deg + 15) >> 4;
    int last = rpe - 1;
    auto ldpos = [&](int t) {
      int p = rp + t * 16 + li;
      return p > last ? last : p;
    };

    // pipeline prologue: tiles 0 and 1 staged; g for tile 0 in flight
    int pA = ldpos(0), pB = ldpos(1);
    int cA = ccol[pA], cB = ccol[pB];
    bf16x8 eA = *(const bf16x8*)(efb + (size_t)pA * ED + lg * 8);
    bf16x8 eB = *(const bf16x8*)(efb + (size_t)pB * ED + lg * 8);
    const short* gpA = g2 + (size_t)cA * 128 + w * 64 + lg * 16;
    bf16x8 gA0 = *(const bf16x8*)gpA;
    bf16x8 gA1 = *(const bf16x8*)(gpA + 8);

    for (int t = 0; t < ntiles; ++t) {
      // prefetch tile t+1's g and tile t+2's pos/col/efb
      const short* gpB = g2 + (size_t)cB * 128 + w * 64 + lg * 16;
      bf16x8 gB0 = *(const bf16x8*)gpB;
      bf16x8 gB1 = *(const bf16x8*)(gpB + 8);
      int pC = ldpos(t + 2);
      int cC = ccol[pC];
      bf16x8 eC = *(const bf16x8*)(efb + (size_t)pC * ED + lg * 8);
      // compute tile t
      f32x4 a0 = __builtin_amdgcn_mfma_f32_16x16x32_bf16(wa[0], eA, (f32x4){0.f,0.f,0.f,0.f}, 0, 0, 0);
      f32x4 a1 = __builtin_amdgcn_mfma_f32_16x16x32_bf16(wa[1], eA, (f32x4){0.f,0.f,0.f,0.f}, 0, 0, 0);
      f32x4 a2 = __builtin_amdgcn_mfma_f32_16x16x32_bf16(wa[2], eA, (f32x4){0.f,0.f,0.f,0.f}, 0, 0, 0);
      f32x4 a3 = __builtin_amdgcn_mfma_f32_16x16x32_bf16(wa[3], eA, (f32x4){0.f,0.f,0.f,0.f}, 0, 0, 0);
      if ((t * 16 + li) < deg) {
        f32x4 v0 = a0 + sreg[0] + bf8lo(gA0);
        f32x4 v1 = a1 + sreg[1] + bf8hi(gA0);
        f32x4 v2 = a2 + sreg[2] + bf8lo(gA1);
        f32x4 v3 = a3 + sreg[3] + bf8hi(gA1);
        #pragma unroll
        for (int r = 0; r < 4; ++r) {
          psum[0][r] += (v0[r] > 0.f ? v0[r] : 0.f);
          psum[1][r] += (v1[r] > 0.f ? v1[r] : 0.f);
          psum[2][r] += (v2[r] > 0.f ? v2[r] : 0.f);
          psum[3][r] += (v3[r] > 0.f ? v3[r] : 0.f);
        }
      }
      // rotate
      cB = cC; eA = eB; eB = eC;
      gA0 = gB0; gA1 = gB1;
    }

    // reduce over the 16 li-lanes (edges), store this wave's col-half
    #pragma unroll
    for (int nt = 0; nt < 4; ++nt)
      #pragma unroll
      for (int r = 0; r < 4; ++r) {
        float v = psum[nt][r];
        v += __shfl_xor(v, 1);
        v += __shfl_xor(v, 2);
        v += __shfl_xor(v, 4);
        v += __shfl_xor(v, 8);
        psum[nt][r] = v;
      }
    if (li == 0) {
      #pragma unroll
      for (int nt = 0; nt < 4; ++nt)
        *(f32x4*)(hsum + (size_t)node * 128 + w * 64 + nt * 16 + lg * 4) = psum[nt];
    }
  }
}

// --- out = Hsum @ W2 + deg*b2 ; 4 waves x 16 rows per block (MFMA) ---
__global__ __launch_bounds__(256) void out_kernel(const float* __restrict__ hsum,
                                                  const short* __restrict__ w2t,
                                                  const float* __restrict__ b2,
                                                  const int* __restrict__ row_ptr,
                                                  float* __restrict__ out, int N) {
  int lane = threadIdx.x & 63, w = threadIdx.x >> 6;
  int li = lane & 15, lg = lane >> 4;
  int base = blockIdx.x * 64 + w * 16;
  int rowm = base + li;
  if (rowm >= N) rowm = N - 1;
  float breg[8];
  #pragma unroll
  for (int nt = 0; nt < 8; ++nt) breg[nt] = b2[nt * 16 + li];
  f32x4 acc[8];
  #pragma unroll
  for (int nt = 0; nt < 8; ++nt) acc[nt] = (f32x4){0.f, 0.f, 0.f, 0.f};
  #pragma unroll
  for (int kc = 0; kc < 4; ++kc) {
    f32x4 f0 = *(const f32x4*)(hsum + (size_t)rowm * 128 + kc * 32 + lg * 8);
    f32x4 f1 = *(const f32x4*)(hsum + (size_t)rowm * 128 + kc * 32 + lg * 8 + 4);
    bf16x8 a;
    #pragma unroll
    for (int j = 0; j < 4; ++j) { a[j] = f2bf(f0[j]); a[4 + j] = f2bf(f1[j]); }
    #pragma unroll
    for (int nt = 0; nt < 8; ++nt) {
      bf16x8 bb = *(const bf16x8*)(w2t + (nt * 16 + li) * 128 + kc * 32 + lg * 8);
      acc[nt] = __builtin_amdgcn_mfma_f32_16x16x32_bf16(a, bb, acc[nt], 0, 0, 0);
    }
  }
  #pragma unroll
  for (int r = 0; r < 4; ++r) {
    int row = base + lg * 4 + r;
    if (row < N) {
      float dg = (float)(row_ptr[row + 1] - row_ptr[row]);
      #pragma unroll
      for (int nt = 0; nt < 8; ++nt)
        out[(size_t)row * 128 + nt * 16 + li] = acc[nt][r] + dg * breg[nt];
    }
  }
}

extern "C" void kernel_launch(void* const* d_in, const int* in_sizes, int n_in,
                              void* d_out, int out_size, void* d_ws, size_t ws_size,
                              hipStream_t stream) {
  const float* h  = (const float*)d_in[0];
  const void*  ei = d_in[1];
  const float* ef = (const float*)d_in[2];
  const float* W1 = (const float*)d_in[4];
  const float* b1 = (const float*)d_in[5];
  const float* W2 = (const float*)d_in[6];
  const float* b2 = (const float*)d_in[7];
  float* out = (float*)d_out;
  int N = in_sizes[0] / ND;
  int E = in_sizes[2] / ED;

  char* ws = (char*)d_ws;
  size_t off = 0;
  auto alloc = [&](size_t bytes) {
    size_t o = off;
    off = (off + bytes + 255) & ~(size_t)255;
    return o;
  };
  int*          counts  = (int*)(ws + alloc((size_t)N * 4));
  int*          row_ptr = (int*)(ws + alloc((size_t)(N + 1) * 4));
  int*          rank    = (int*)(ws + alloc((size_t)E * 4));
  unsigned int* rc      = (unsigned int*)(ws + alloc((size_t)E * 4));
  short*        w12t    = (short*)(ws + alloc(256 * 128 * 2));
  short*        w1eA    = (short*)(ws + alloc(8 * 64 * 8 * 2));
  short*        w2t     = (short*)(ws + alloc(128 * 128 * 2));
  float*        s2      = (float*)(ws + alloc((size_t)N * 128 * 4));
  short*        g2      = (short*)(ws + alloc((size_t)N * 128 * 2));
  float*        hsumb   = (float*)(ws + alloc((size_t)N * 128 * 4));
  short*        efb     = (short*)(ws + alloc((size_t)E * ED * 2));
  int*          ccol    = (int*)(ws + alloc((size_t)E * 4));

  int SGB = (N + 63) >> 6;
  int SCB = (4 * E + 255) >> 8;

  hipMemsetAsync(counts, 0, (size_t)N * 4, stream);   // MUST precede prep_hist (R11 race)
  prep_hist_kernel<<<128 + (E + 255) / 256, 256, 0, stream>>>(
      W1, W2, ei, counts, rank, rc, w12t, w1eA, w2t, E);
  scan_kernel<<<1, 1024, 0, stream>>>(counts, row_ptr, N);
  scatter_sg_kernel<<<SGB + SCB, 256, 0, stream>>>(
      ef, row_ptr, rank, rc, h, w12t, b1, efb, ccol, s2, g2, N, E);
  layer1_kernel<<<NL1, 128, 0, stream>>>(s2, g2, efb, ccol, w1eA, row_ptr, hsumb, N);
  out_kernel<<<(N + 63) / 64, 256, 0, stream>>>(hsumb, w2t, b2, row_ptr, out, N);
}